// Round 5
// baseline (239.262 us; speedup 1.0000x reference)
//
#include <hip/hip_runtime.h>

typedef unsigned short u16;
typedef unsigned int u32;
typedef __bf16 bf16x8 __attribute__((ext_vector_type(8)));
typedef float f32x4 __attribute__((ext_vector_type(4)));
typedef u16 u16x4 __attribute__((ext_vector_type(4)));
typedef __attribute__((address_space(1))) void* as1_t;
typedef __attribute__((address_space(3))) void* as3_t;

#define LOG2E 1.4426950408889634f
#define MFMA(a,b,c) __builtin_amdgcn_mfma_f32_16x16x32_bf16(a,b,c,0,0,0)

__device__ __forceinline__ u16 f2bf(float f){
  u32 u = __float_as_uint(f);
  return (u16)((u + 0x7FFFu + ((u >> 16) & 1u)) >> 16);
}
__device__ __forceinline__ float bf2f(u16 x){
  return __uint_as_float(((u32)x) << 16);
}
#if __has_builtin(__builtin_amdgcn_cvt_pk_bf16_f32)
__device__ __forceinline__ u16x4 pk4(float a, float b, float c, float d){
  auto lo = __builtin_amdgcn_cvt_pk_bf16_f32(a,b);
  auto hi = __builtin_amdgcn_cvt_pk_bf16_f32(c,d);
  union { u16x4 v; u32 w[2]; } u;
  u.w[0] = __builtin_bit_cast(u32, lo);
  u.w[1] = __builtin_bit_cast(u32, hi);
  return u.v;
}
#else
__device__ __forceinline__ u16x4 pk4(float a, float b, float c, float d){
  u16x4 r = { f2bf(a), f2bf(b), f2bf(c), f2bf(d) };
  return r;
}
#endif
__device__ __forceinline__ void gld16(const u16* gp, u16* lp){
  __builtin_amdgcn_global_load_lds((as1_t)(u16*)gp, (as3_t)lp, 16, 0, 0);
}

#define SBAR  __builtin_amdgcn_s_barrier()
#define SCHB  __builtin_amdgcn_sched_barrier(0)
#define SP1   __builtin_amdgcn_s_setprio(1)
#define SP0   __builtin_amdgcn_s_setprio(0)
#define WAITL0 asm volatile("s_waitcnt lgkmcnt(0)" ::: "memory")
#define WAITV6 asm volatile("s_waitcnt vmcnt(6)" ::: "memory")
#define WV0 asm volatile("s_waitcnt vmcnt(0)" ::: "memory")
#define WV2 asm volatile("s_waitcnt vmcnt(2)" ::: "memory")
#define WV4 asm volatile("s_waitcnt vmcnt(4)" ::: "memory")

// ---------------- prep: cast both inputs + all 5 weight transposes, ONE launch ----------------
__global__ void prep_kernel(const float* __restrict__ vis, u16* __restrict__ vis16,
                            const float* __restrict__ txt, u16* __restrict__ txt16,
                            const float* __restrict__ Wq, const float* __restrict__ Wk,
                            const float* __restrict__ Wv, const float* __restrict__ Wo,
                            u16* __restrict__ T0, u16* __restrict__ T1,
                            u16* __restrict__ T2, u16* __restrict__ T3,
                            u16* __restrict__ T4){
  int bid = blockIdx.x;
  if(bid < 8192){
    const float* src = (bid < 4096) ? vis : txt;
    u16* dst = (bid < 4096) ? vis16 : txt16;
    int idx = ((bid & 4095)*256 + threadIdx.x)*4;
    float4 v = *(const float4*)(src + idx);
    *(u16x4*)(dst + idx) = pk4(v.x, v.y, v.z, v.w);
    return;
  }
  int rr = bid - 8192;
  int wi = rr >> 8, tile = rr & 255;
  const float* W; u16* WT;
  switch(wi){
    case 0: W = Wq; WT = T0; break;
    case 1: W = Wv; WT = T1; break;
    case 2: W = Wk; WT = T2; break;
    case 3: W = Wv; WT = T3; break;
    default: W = Wo; WT = T4; break;
  }
  __shared__ u16 t[64][65];
  int bn = (tile & 15)*64, bk = (tile >> 4)*64;
  int c = threadIdx.x & 63, r0 = threadIdx.x >> 6;
  #pragma unroll
  for(int j=0;j<64;j+=4){
    int r = r0 + j;
    t[r][c] = f2bf(W[(bk + r)*1024 + bn + c]);
  }
  __syncthreads();
  #pragma unroll
  for(int j=0;j<64;j+=4){
    int r = r0 + j;
    WT[(bn + r)*1024 + bk + c] = t[c][r];
  }
}

// ---------------- merged projection GEMM: 256x256, 2-buf, read-ahead-1-phase pipeline --------
// 8 waves 2Mx4N (128x64/wave). 4 phases/K-tile, 16 MFMA each. ds_reads feed the NEXT phase
// (double-buffered frag regs) -> compiler emits counted lgkmcnt, read-return overlaps MFMA.
// STAGED HALVES == READ SETS (round-4 bugfix):
//   A-half h = rows {h*64+j} u {128+h*64+j}, j in [0,64)  -> LDA_(mh) needs exactly A-half mh
//   B-half h = rows with (r>>5)&1 == h                    -> LDB_(nh) needs exactly B-half nh
// Staging: 1 half/phase into the IDLE buffer; counted vmcnt at phase ends (before next SBAR),
// never 0 in-loop. Last tile peeled.
// grid (16 m, 8 n, 2 z): bid%8 = m%8 -> A-panel sharers co-located per XCD.
__global__ __launch_bounds__(512, 2)
void proj_gemm_kernel(const u16* __restrict__ Avis, const u16* __restrict__ Atxt,
                      const u16* __restrict__ Wvis, const u16* __restrict__ Wtxt,
                      u16* __restrict__ Qb, u16* __restrict__ V2t,
                      u16* __restrict__ Kb, u16* __restrict__ Vt)
{
  const u16 *A, *Bt; u16 *Cn, *Ct;
  if(blockIdx.z == 0){ A = Avis; Bt = Wvis; Cn = Qb; Ct = V2t; }
  else               { A = Atxt; Bt = Wtxt; Cn = Kb; Ct = Vt;  }
  // 128 KiB: buf b at b*32768 (u16): A halves at +0,+8192; B halves at +16384,+24576.
  __shared__ u16 lds[65536];
  const int tid = threadIdx.x, w = tid >> 6, lane = tid & 63;
  const int quad = lane >> 4, cl = lane & 15;
  const int wr = w >> 2, wc = w & 3;            // 2 M-halves x 4 N-quarters
  const int bm = blockIdx.x*256, bn = blockIdx.y*256;
  const int sx0 = ((quad    ) ^ (cl & 7)) << 3; // kc=0 16B-slot (u16 units)
  const int sx1 = ((quad + 4) ^ (cl & 7)) << 3; // kc=1
  const int arow = ((wr << 6) + cl) << 6;       // local row in A-half: (wr*64 + cl)*64
  const int brow = (((wc << 5) + cl) << 6) + 16384; // local row in B-half: (wc*32 + cl)*64

  f32x4 acc[8][4];
  #pragma unroll
  for(int a=0;a<8;a++)
    #pragma unroll
    for(int b=0;b<4;b++){ f32x4 z = {0.f,0.f,0.f,0.f}; acc[a][b] = z; }
  bf16x8 af0[4][2], af1[4][2], bfv0[2][2], bfv1[2][2];

  // ---- staging: one half (128 rows x 64 K = 16 KiB, 2 gld16/thread), linear LDS dest,
  // swizzle on GLOBAL src (involution, rule #21). Global row mapping differs per half kind.
  // A half h: gr = h*64 + (r&63) + ((r>>6)<<7)
#define STGA(gbase, bufo, h, kk) { \
    _Pragma("unroll") \
    for(int ii=0;ii<2;ii++){ \
      int slot_ = ii*512 + tid; int r_ = slot_ >> 3, cs_ = slot_ & 7; \
      int gr_ = (h)*64 + (r_ & 63) + ((r_ >> 6) << 7); \
      gld16(A + (size_t)((gbase) + gr_)*1024 + (kk) + ((cs_ ^ (r_ & 7)) << 3), \
            lds + (bufo) + (h)*8192 + (ii*512 + (w << 6))*8); } }
  // B half h: gr = (r>>5)*64 + h*32 + (r&31)
#define STGB(gbase, bufo, h, kk) { \
    _Pragma("unroll") \
    for(int ii=0;ii<2;ii++){ \
      int slot_ = ii*512 + tid; int r_ = slot_ >> 3, cs_ = slot_ & 7; \
      int gr_ = ((r_ >> 5) << 6) + (h)*32 + (r_ & 31); \
      gld16(Bt + (size_t)((gbase) + gr_)*1024 + (kk) + ((cs_ ^ (r_ & 7)) << 3), \
            lds + (bufo) + 16384 + (h)*8192 + (ii*512 + (w << 6))*8); } }

#define LDA_(bo, mh, dst) { \
    _Pragma("unroll") \
    for(int q_=0;q_<4;q_++){ \
      int ro_ = (bo) + (mh)*8192 + arow + (q_ << 10); \
      dst[q_][0] = *(const bf16x8*)(lds + ro_ + sx0); \
      dst[q_][1] = *(const bf16x8*)(lds + ro_ + sx1); } }

#define LDB_(bo, nh, dst) { \
    _Pragma("unroll") \
    for(int j_=0;j_<2;j_++){ \
      int ro_ = (bo) + (nh)*8192 + brow + (j_ << 10); \
      dst[j_][0] = *(const bf16x8*)(lds + ro_ + sx0); \
      dst[j_][1] = *(const bf16x8*)(lds + ro_ + sx1); } }

#define MM_(a_, b_, mh, nh) { \
    _Pragma("unroll") \
    for(int q_=0;q_<4;q_++) \
      _Pragma("unroll") \
      for(int j_=0;j_<2;j_++){ \
        acc[(mh)*4+q_][(nh)*2+j_] = MFMA(a_[q_][0], b_[j_][0], acc[(mh)*4+q_][(nh)*2+j_]); \
        acc[(mh)*4+q_][(nh)*2+j_] = MFMA(a_[q_][1], b_[j_][1], acc[(mh)*4+q_][(nh)*2+j_]); } }

  // prologue: stage tile0 {A0,B0,B1}; retire A0; read-ahead af0(0); stage A1(0); retire B0,B1
  STGA(bm, 0, 0, 0);              // A-half0(0)
  STGB(bn, 0, 0, 0);              // B-half0(0)
  STGB(bn, 0, 1, 0);              // B-half1(0)
  WV4;                            // retire A-half0(0); B halves stay in flight
  SBAR;
  LDA_(0, 0, af0);                // read-ahead af0(tile0)  [needs A-half0 only]
  STGA(bm, 0, 1, 0);              // A-half1(0)
  WV2;                            // retire B-half0,1(0); A-half1(0) in flight

  #pragma unroll 2
  for(int t=0; t<15; ++t){
    const int c  = (t & 1) << 15;       // current buffer (u16 offset)
    const int nb = ((t+1) & 1) << 15;   // idle buffer <- tile t+1
    const int ts = (t+1) << 6;
    // P1: MFMA (0,0) on preloaded af0 + bfv0 (read now); stage A0(t+1)
    SBAR;
    LDB_(c, 0, bfv0); LDB_(c, 1, bfv1);
    STGA(bm, nb, 0, ts);
    SP1; MM_(af0, bfv0, 0, 0); SP0;
    WV2;                                // retire A-half1(t) for P2's LDA
    // P2: MFMA (0,1); read af1(t); stage B0(t+1)
    SBAR;
    LDA_(c, 1, af1);
    STGB(bn, nb, 0, ts);
    SP1; MM_(af0, bfv1, 0, 1); SP0;
    // P3: MFMA (1,1); stage B1(t+1)
    SBAR;
    STGB(bn, nb, 1, ts);
    SP1; MM_(af1, bfv1, 1, 1); SP0;
    WV4;                                // retire A-half0(t+1) for P4's read-ahead
    // P4: MFMA (1,0); read-ahead af0(t+1) from idle buf; stage A1(t+1)
    SBAR;
    LDA_(nb, 0, af0);
    STGA(bm, nb, 1, ts);
    SP1; MM_(af1, bfv0, 1, 0); SP0;
    WV2;                                // retire B-half0,1(t+1) for next P1
  }
  // tail: tile 15 (buf1), af0 already preloaded
  WV0;
  SBAR;
  LDB_(32768, 0, bfv0); LDB_(32768, 1, bfv1);
  LDA_(32768, 1, af1);
  MM_(af0, bfv0, 0, 0);
  MM_(af0, bfv1, 0, 1);
  MM_(af1, bfv1, 1, 1);
  MM_(af1, bfv0, 1, 0);
#undef STGA
#undef STGB
#undef LDA_
#undef LDB_
#undef MM_

  if(bn < 1024){
    #pragma unroll
    for(int mf=0; mf<8; mf++){
      int m0 = bm + wr*128 + mf*16 + quad*4;
      #pragma unroll
      for(int nf=0; nf<4; nf++){
        int n = bn + wc*64 + nf*16 + cl;
        int h = n >> 6, d = n & 63;
        #pragma unroll
        for(int i2=0;i2<4;i2++){
          int m = m0 + i2; int b = m >> 10, s = m & 1023;
          Cn[(((size_t)(b*16 + h)*1024 + s) << 6) + d] = f2bf(acc[mf][nf][i2]);
        }
      }
    }
  } else {
    #pragma unroll
    for(int mf=0; mf<8; mf++){
      int m0 = bm + wr*128 + mf*16 + quad*4;
      int b = m0 >> 10, s = m0 & 1023;
      #pragma unroll
      for(int nf=0; nf<4; nf++){
        int nn = bn - 1024 + wc*64 + nf*16 + cl;
        int h = nn >> 6, d = nn & 63;
        *(u16x4*)(Ct + (((size_t)(b*16 + h)*64 + d) << 10) + s) =
            pk4(acc[mf][nf][0], acc[mf][nf][1], acc[mf][nf][2], acc[mf][nf][3]);
      }
    }
  }
}

// ============ out_gemm body: 256x128 (BK=64) 3-deep pipelined (round-2 structure) ============
__device__ __forceinline__ void gemm_pipe(const u16* __restrict__ A,
                                          const u16* __restrict__ Bt,
                                          int bm, int bn,
                                          u16* __restrict__ lds,
                                          f32x4 (&acc)[4][4],
                                          int tid, int w, int quad, int cl,
                                          int wr, int wc)
{
  const int sx0 = ((quad    ) ^ (cl & 7)) << 3;
  const int sx1 = ((quad + 4) ^ (cl & 7)) << 3;
  const int arow = ((wr << 6) + cl) << 6;
  const int brow = (((wc << 6) + cl) << 6) + 16384;
  bf16x8 af[4][2], bfv[2][2];

#define STAGE128(G, gbase, dsto, kk) { \
    _Pragma("unroll") \
    for(int ii=0;ii<2;ii++){ \
      int slot_ = ii*512 + tid; int r_ = slot_ >> 3, cs_ = slot_ & 7; \
      gld16((G) + (size_t)((gbase) + r_)*1024 + (kk) + ((cs_ ^ (r_ & 7)) << 3), \
            lds + (dsto) + (ii*512 + (w << 6))*8); } }

#define LDA_(bo) { \
    _Pragma("unroll") \
    for(int m_=0;m_<4;m_++){ \
      int ro_ = (bo) + arow + (m_ << 10); \
      af[m_][0] = *(const bf16x8*)(lds + ro_ + sx0); \
      af[m_][1] = *(const bf16x8*)(lds + ro_ + sx1); } }

#define LDB_(bo, nh) { \
    _Pragma("unroll") \
    for(int j_=0;j_<2;j_++){ \
      int ro_ = (bo) + brow + (((nh)*2 + j_) << 10); \
      bfv[j_][0] = *(const bf16x8*)(lds + ro_ + sx0); \
      bfv[j_][1] = *(const bf16x8*)(lds + ro_ + sx1); } }

#define MM_(nh) { \
    _Pragma("unroll") \
    for(int m_=0;m_<4;m_++) \
      _Pragma("unroll") \
      for(int j_=0;j_<2;j_++){ \
        acc[m_][(nh)*2+j_] = MFMA(af[m_][0], bfv[j_][0], acc[m_][(nh)*2+j_]); \
        acc[m_][(nh)*2+j_] = MFMA(af[m_][1], bfv[j_][1], acc[m_][(nh)*2+j_]); } }

  STAGE128(A , bm      , 0,          0);
  STAGE128(A , bm + 128, 8192,       0);
  STAGE128(Bt, bn      , 16384,      0);
  STAGE128(A , bm      , 24576,      64);
  STAGE128(A , bm + 128, 24576+8192, 64);
  STAGE128(Bt, bn      , 24576+16384,64);
  WAITV6; SBAR;

  #pragma unroll 2
  for(int t=0;t<16;t++){
    const int c  = (t % 3) * 24576;
    const int n2 = ((t+2) % 3) * 24576;
    const int ts = ((t+2) & 15) << 6;
    LDA_(c); LDB_(c, 0);
    STAGE128(A, bm      , n2,        ts);
    STAGE128(A, bm + 128, n2 + 8192, ts);
    SBAR; WAITL0; SCHB;
    SP1; MM_(0); SP0;
    SBAR;
    LDB_(c, 1);
    STAGE128(Bt, bn, n2 + 16384, ts);
    SBAR; WAITL0; SCHB;
    SP1; MM_(1); SP0;
    WAITV6;
    SBAR;
  }
#undef STAGE128
#undef LDA_
#undef LDB_
#undef MM_
}

// ---------------- output GEMM: out[8192 x 1024] f32 = A * WoT, 256x128 3-deep pipeline -------
__global__ __launch_bounds__(512, 2)
void out_gemm_kernel(const u16* __restrict__ A, const u16* __restrict__ Bt,
                     float* __restrict__ Cf)
{
  __shared__ u16 lds[73728];
  const int tid = threadIdx.x, w = tid >> 6, lane = tid & 63;
  const int quad = lane >> 4, cl = lane & 15;
  const int wr = w >> 1, wc = w & 1;
  const int bm = blockIdx.x*256, bn = blockIdx.y*128;

  f32x4 acc[4][4];
  #pragma unroll
  for(int a=0;a<4;a++)
    #pragma unroll
    for(int b=0;b<4;b++){ f32x4 z = {0.f,0.f,0.f,0.f}; acc[a][b] = z; }

  gemm_pipe(A, Bt, bm, bn, lds, acc, tid, w, quad, cl, wr, wc);

  #pragma unroll
  for(int mf=0; mf<4; mf++)
    #pragma unroll
    for(int nf=0; nf<4; nf++)
      #pragma unroll
      for(int i=0;i<4;i++){
        int m = bm + wr*64 + mf*16 + quad*4 + i;
        int n = bn + wc*64 + nf*16 + cl;
        Cf[(size_t)m*1024 + n] = acc[mf][nf][i];
      }
}

// ---------------- attention (vis): 8 waves x 16 q-rows; grid x=bh (XCD-grouped K/V) ----------------
__global__ __launch_bounds__(512, 4)
void attn_vis_kernel(const u16* __restrict__ Q, const u16* __restrict__ Kc,
                     const u16* __restrict__ Vt, u16* __restrict__ visA,
                     float* __restrict__ rl_g)
{
  __shared__ u16 lds[17408];   // 34816 B
  u16* Pl  = lds;              // P[q=128][72]; Q staged here first ([c8][128][8]=8192)
  u16* Kst = lds + 9216;       // [c8][64][8] = 4096 u16
  u16* Vst = lds + 13312;      // [d=64][ch^][8] swizzled = 4096 u16
  const int tid = threadIdx.x, w = tid>>6, lane = tid&63;
  const int quad = lane>>4, cl = lane&15;
  const int bh = blockIdx.x, q0 = blockIdx.y*128;   // XCD = bh % 8
  const u16* Qh  = Q  + (size_t)bh*65536;
  const u16* Kh  = Kc + (size_t)bh*65536;
  const u16* Vth = Vt + (size_t)bh*65536;

  #pragma unroll
  for(int i=0;i<2;i++){
    int slot = i*512 + tid;
    int c = slot >> 7, r = slot & 127;
    gld16(Qh + (size_t)(q0 + r)*64 + c*8, Pl + slot*8);
  }
  __syncthreads();
  bf16x8 qf[2];
  #pragma unroll
  for(int kk=0;kk<2;kk++)
    qf[kk] = *(const bf16x8*)(Pl + ((kk*4+quad)*128 + w*16 + cl)*8);
  __syncthreads();   // Pl now becomes the P buffer

  float lrun = 0.f;
  f32x4 oacc[4];
  #pragma unroll
  for(int dt=0;dt<4;dt++){ f32x4 z = {0.f,0.f,0.f,0.f}; oacc[dt] = z; }

  for(int kt=0;kt<16;kt++){
    __syncthreads();
    {
      int slot = tid;
      { int c = slot >> 6, r = slot & 63;
        gld16(Kh + (size_t)(kt*64 + r)*64 + c*8, Kst + slot*8); }
      { int d = slot >> 3, ch = slot & 7;
        gld16(Vth + (size_t)d*1024 + kt*64 + (ch^(d&7))*8, Vst + slot*8); }
    }
    __syncthreads();
    #pragma unroll
    for(int mtk=0;mtk<4;mtk++){
      f32x4 s = {0.f,0.f,0.f,0.f};
      #pragma unroll
      for(int kk=0;kk<2;kk++){
        bf16x8 ka = *(const bf16x8*)(Kst + ((kk*4+quad)*64 + mtk*16 + cl)*8);
        s = MFMA(ka, qf[kk], s);
      }
      float p0 = __builtin_amdgcn_exp2f(s[0]*LOG2E);
      float p1 = __builtin_amdgcn_exp2f(s[1]*LOG2E);
      float p2 = __builtin_amdgcn_exp2f(s[2]*LOG2E);
      float p3 = __builtin_amdgcn_exp2f(s[3]*LOG2E);
      lrun += (p0+p1)+(p2+p3);
      *(u16x4*)(Pl + (w*16 + cl)*72 + mtk*16 + quad*4) = pk4(p0,p1,p2,p3);
    }
    bf16x8 pa[2];
    #pragma unroll
    for(int kk=0;kk<2;kk++)
      pa[kk] = *(const bf16x8*)(Pl + (w*16 + cl)*72 + kk*32 + quad*8);
    #pragma unroll
    for(int dt=0;dt<4;dt++){
      int d = dt*16 + cl;
      #pragma unroll
      for(int kk=0;kk<2;kk++){
        bf16x8 vb = *(const bf16x8*)(Vst + d*64 + (((kk*4+quad)^(d&7))*8));
        oacc[dt] = MFMA(pa[kk], vb, oacc[dt]);
      }
    }
  }
  lrun += __shfl_xor(lrun, 16, 64);
  lrun += __shfl_xor(lrun, 32, 64);
  float rl = 1.f/lrun;
  if(quad == 0) rl_g[bh*1024 + q0 + w*16 + cl] = rl;
  const int b = bh >> 4, h = bh & 15;
  #pragma unroll
  for(int i=0;i<4;i++){
    float rr = __shfl(rl, quad*4 + i, 16);
    int q = q0 + w*16 + quad*4 + i;
    #pragma unroll
    for(int dt=0;dt<4;dt++)
      visA[(size_t)(b*1024 + q)*1024 + h*64 + dt*16 + cl] = f2bf(oacc[dt][i]*rr);
  }
}

// ---------------- attention (txt): 8 waves x 16 k-rows; grid x=bh; rl applied in-kernel ----------
__global__ __launch_bounds__(512, 4)
void attn_txt_kernel(const u16* __restrict__ Kc, const u16* __restrict__ Q,
                     const u16* __restrict__ V2t, const float* __restrict__ rl_g,
                     u16* __restrict__ txtA)
{
  __shared__ u16 lds[17408];
  u16* Pl  = lds;              // P^T[k=128][72]; K-block staged here first
  u16* Qst = lds + 9216;       // [c8][64][8]
  u16* Vst = lds + 13312;      // [d][ch^][8] swizzled (contraction = q)
  const int tid = threadIdx.x, w = tid>>6, lane = tid&63;
  const int quad = lane>>4, cl = lane&15;
  const int bh = blockIdx.x, k0 = blockIdx.y*128;   // XCD = bh % 8
  const u16* Kh  = Kc  + (size_t)bh*65536;
  const u16* Qh  = Q   + (size_t)bh*65536;
  const u16* Vth = V2t + (size_t)bh*65536;

  #pragma unroll
  for(int i=0;i<2;i++){
    int slot = i*512 + tid;
    int c = slot >> 7, r = slot & 127;
    gld16(Kh + (size_t)(k0 + r)*64 + c*8, Pl + slot*8);
  }
  __syncthreads();
  bf16x8 kb[2];
  #pragma unroll
  for(int kk=0;kk<2;kk++)
    kb[kk] = *(const bf16x8*)(Pl + ((kk*4+quad)*128 + w*16 + cl)*8);
  __syncthreads();

  f32x4 oacc[4];
  #pragma unroll
  for(int dt=0;dt<4;dt++){ f32x4 z = {0.f,0.f,0.f,0.f}; oacc[dt] = z; }

  for(int qt=0;qt<16;qt++){
    __syncthreads();
    {
      int slot = tid;
      { int c = slot >> 6, r = slot & 63;
        gld16(Qh + (size_t)(qt*64 + r)*64 + c*8, Qst + slot*8); }
      { int d = slot >> 3, ch = slot & 7;
        gld16(Vth + (size_t)d*1024 + qt*64 + (ch^(d&7))*8, Vst + slot*8); }
    }
    __syncthreads();
    f32x4 rv[4];
    #pragma unroll
    for(int mtq=0;mtq<4;mtq++)
      rv[mtq] = *(const f32x4*)(rl_g + bh*1024 + qt*64 + mtq*16 + quad*4);
    #pragma unroll
    for(int mtq=0;mtq<4;mtq++){
      f32x4 s = {0.f,0.f,0.f,0.f};
      #pragma unroll
      for(int kk=0;kk<2;kk++){
        bf16x8 qa = *(const bf16x8*)(Qst + ((kk*4+quad)*64 + mtq*16 + cl)*8);
        s = MFMA(qa, kb[kk], s);
      }
      float p0 = __builtin_amdgcn_exp2f(s[0]*LOG2E)*rv[mtq][0];
      float p1 = __builtin_amdgcn_exp2f(s[1]*LOG2E)*rv[mtq][1];
      float p2 = __builtin_amdgcn_exp2f(s[2]*LOG2E)*rv[mtq][2];
      float p3 = __builtin_amdgcn_exp2f(s[3]*LOG2E)*rv[mtq][3];
      *(u16x4*)(Pl + (w*16 + cl)*72 + mtq*16 + quad*4) = pk4(p0,p1,p2,p3);
    }
    bf16x8 pa[2];
    #pragma unroll
    for(int kk=0;kk<2;kk++)
      pa[kk] = *(const bf16x8*)(Pl + (w*16 + cl)*72 + kk*32 + quad*8);
    #pragma unroll
    for(int dt=0;dt<4;dt++){
      int d = dt*16 + cl;
      #pragma unroll
      for(int kk=0;kk<2;kk++){
        bf16x8 vb = *(const bf16x8*)(Vst + d*64 + (((kk*4+quad)^(d&7))*8));
        oacc[dt] = MFMA(pa[kk], vb, oacc[dt]);
      }
    }
  }
  const int b = bh >> 4, h = bh & 15;
  #pragma unroll
  for(int i=0;i<4;i++){
    int k = k0 + w*16 + quad*4 + i;
    #pragma unroll
    for(int dt=0;dt<4;dt++)
      txtA[(size_t)(b*1024 + k)*1024 + h*64 + dt*16 + cl] = f2bf(oacc[dt][i]);
  }
}

extern "C" void kernel_launch(void* const* d_in, const int* in_sizes, int n_in,
                              void* d_out, int out_size, void* d_ws, size_t ws_size,
                              hipStream_t stream)
{
  const float* vis = (const float*)d_in[0];
  const float* txt = (const float*)d_in[1];
  const float* Wq  = (const float*)d_in[2];
  const float* Wk  = (const float*)d_in[3];
  const float* Wv  = (const float*)d_in[4];
  const float* Wo  = (const float*)d_in[5];
  float* out = (float*)d_out;

  char* ws = (char*)d_ws;
  const size_t MB = 1u << 20;
  u16* vis16 = (u16*)(ws + 0);           // later: visA
  u16* txt16 = (u16*)(ws + 8*MB);        // later: txtA (contiguous with visA for out GEMM)
  u16* Wvis  = (u16*)(ws + 16*MB);       // [WqT | WvT]
  u16* Wtxt  = (u16*)(ws + 20*MB);       // [WkT | WvT]
  u16* Qb    = (u16*)(ws + 24*MB);
  u16* Kb    = (u16*)(ws + 32*MB);
  u16* Vt    = (u16*)(ws + 40*MB);       // V^T  [b][h][d][s]  (from txt proj)
  u16* V2t   = (u16*)(ws + 48*MB);       // V2^T [b][h][d][s]  (from vis proj)
  float* rl_g = (float*)(ws + 56*MB);
  u16* WoT   = (u16*)(ws + 57*MB);
  u16* visA = vis16;  u16* txtA = txt16;

  // 1: cast both inputs + 5 weight transposes
  prep_kernel<<<9472, 256, 0, stream>>>(vis, vis16, txt, txt16,
                                        Wq, Wk, Wv, Wo,
                                        Wvis, Wvis + 1048576, Wtxt, Wtxt + 1048576, WoT);
  // 2: merged projections, 256x256 tiles, read-ahead pipeline, 256 blocks (1/CU)
  proj_gemm_kernel<<<dim3(16,8,2), 512, 0, stream>>>(vis16, txt16, Wvis, Wtxt,
                                                     Qb, V2t, Kb, Vt);
  // 3: attention vis (produces rl); visA overwrites vis16 (dead after projections)
  attn_vis_kernel<<<dim3(64,8), 512, 0, stream>>>(Qb, Kb, Vt, visA, rl_g);
  // 4: attention txt (applies rl in-kernel); txtA overwrites txt16
  attn_txt_kernel<<<dim3(64,8), 512, 0, stream>>>(Kb, Qb, V2t, rl_g, txtA);
  // 5: merged output projection: M=8192 over visA||txtA (contiguous), f32 out
  out_gemm_kernel<<<dim3(32,8), 512, 0, stream>>>(visA, WoT, out);
}